// Round 7
// baseline (194.301 us; speedup 1.0000x reference)
//
#include <hip/hip_runtime.h>
#include <cstdint>
#include <cstddef>

#define B_ 4
#define L_ 4096
#define E_ 1024
#define H_ 16
#define D_ 64
#define BH_ 64
#define ST2_ 4160        // 4096 kv + 64 ksum
#define NCH_ 16
#define RPC_ (L_/NCH_)   // 256 k-rows per chunk

__device__ __forceinline__ float sigk(float x) {
    // sigmoid(0.6053*x - 4.102) = 1/(1+exp(4.102 - 0.6053*x))
    return __builtin_amdgcn_rcpf(1.0f + __expf(4.102f - 0.6053f * x));
}

// ---------------- Kernel 1: partial kv[d][e] per (b,h,chunk) ----------------
// No LDS. lane = d: loads K[k][h*64+lane] coalesced, sigk once.
// V row chunk is wave-uniform -> scalar loads (SGPR), FMA = VGPR*SGPR+VGPR.
// Wave w owns e-chunk [16w, 16w+16): acc = 16 VGPRs only.
__global__ void __launch_bounds__(256) kv_partial_kernel(
    const float* __restrict__ K, const float* __restrict__ V,
    float* __restrict__ partial)
{
    const int ch = blockIdx.x & (NCH_ - 1);
    const int bh = blockIdx.x / NCH_;
    const int b = bh >> 4, h = bh & 15;
    const int lane = threadIdx.x & 63;
    const int w = __builtin_amdgcn_readfirstlane(threadIdx.x >> 6);

    const float* Kp = K + (size_t)(b * L_ + ch * RPC_) * E_ + h * D_ + lane;
    const float* Vp = V + (size_t)(b * L_ + ch * RPC_) * E_ + h * D_ + (w << 4);

    float acc[16];
    #pragma unroll
    for (int j = 0; j < 16; ++j) acc[j] = 0.f;
    float ks = 0.f;

    #pragma unroll 2
    for (int k = 0; k < RPC_; ++k) {
        const float phi = sigk(Kp[(size_t)k * E_]);       // per-lane (lane = d)
        const float4* vr = (const float4*)(Vp + (size_t)k * E_);  // uniform
        const float4 v0 = vr[0], v1 = vr[1], v2 = vr[2], v3 = vr[3];
        acc[ 0] = fmaf(phi, v0.x, acc[ 0]);
        acc[ 1] = fmaf(phi, v0.y, acc[ 1]);
        acc[ 2] = fmaf(phi, v0.z, acc[ 2]);
        acc[ 3] = fmaf(phi, v0.w, acc[ 3]);
        acc[ 4] = fmaf(phi, v1.x, acc[ 4]);
        acc[ 5] = fmaf(phi, v1.y, acc[ 5]);
        acc[ 6] = fmaf(phi, v1.z, acc[ 6]);
        acc[ 7] = fmaf(phi, v1.w, acc[ 7]);
        acc[ 8] = fmaf(phi, v2.x, acc[ 8]);
        acc[ 9] = fmaf(phi, v2.y, acc[ 9]);
        acc[10] = fmaf(phi, v2.z, acc[10]);
        acc[11] = fmaf(phi, v2.w, acc[11]);
        acc[12] = fmaf(phi, v3.x, acc[12]);
        acc[13] = fmaf(phi, v3.y, acc[13]);
        acc[14] = fmaf(phi, v3.z, acc[14]);
        acc[15] = fmaf(phi, v3.w, acc[15]);
        ks += phi;                                         // only w==0 stores
    }

    const size_t pbase = ((size_t)ch * BH_ + bh) * ST2_;
    // lane d writes kv[d][16w..16w+16): one full 64B line per lane
    float4* pp = (float4*)(partial + pbase + (lane << 6) + (w << 4));
    pp[0] = make_float4(acc[ 0], acc[ 1], acc[ 2], acc[ 3]);
    pp[1] = make_float4(acc[ 4], acc[ 5], acc[ 6], acc[ 7]);
    pp[2] = make_float4(acc[ 8], acc[ 9], acc[10], acc[11]);
    pp[3] = make_float4(acc[12], acc[13], acc[14], acc[15]);
    if (w == 0) partial[pbase + 4096 + lane] = ks;
}

// -------- Kernel 2: reduce partials -> kvT[e][d] (transposed) + ksum --------
__global__ void __launch_bounds__(256) kv_reduce_kernel(
    const float* __restrict__ partial, float* __restrict__ kvf)
{
    const int bh = blockIdx.x >> 2, dq = blockIdx.x & 3;
    const int t = threadIdx.x, e = t & 63, dl = t >> 6;
    #pragma unroll
    for (int i = 0; i < 4; ++i) {
        const int d = (dq << 4) + (i << 2) + dl;
        float s = 0.f;
        #pragma unroll
        for (int c = 0; c < NCH_; ++c)
            s += partial[((size_t)c * BH_ + bh) * ST2_ + (d << 6) + e];
        kvf[(size_t)bh * ST2_ + (e << 6) + d] = s;      // transposed
    }
    if (dq == 0 && t < 64) {
        float s = 0.f;
        #pragma unroll
        for (int c = 0; c < NCH_; ++c)
            s += partial[((size_t)c * BH_ + bh) * ST2_ + 4096 + t];
        kvf[(size_t)bh * ST2_ + 4096 + t] = s;
    }
}

// ---------------- Kernel 3: out = (phiQ @ kv) / (phiQ @ ksum) ----------------
// No LDS. lane = q-row: phiQ row in 64 VGPRs (compile-time indexed),
// kvT rows arrive wave-uniform via scalar loads (SGPR operand in FMA).
__device__ __forceinline__ float dot64(const float* __restrict__ kr,
                                       const float ph[64]) {
    float a = 0.f;
    #pragma unroll
    for (int i = 0; i < 16; ++i) {
        const float4 kk = ((const float4*)kr)[i];       // uniform -> SGPR
        a = fmaf(ph[4*i+0], kk.x, a);
        a = fmaf(ph[4*i+1], kk.y, a);
        a = fmaf(ph[4*i+2], kk.z, a);
        a = fmaf(ph[4*i+3], kk.w, a);
    }
    return a;
}

__global__ void __launch_bounds__(256, 1) attn_out_kernel(
    const float* __restrict__ Q, const float* __restrict__ kvf,
    float* __restrict__ out)
{
    const int bh = blockIdx.x >> 4;
    const int lane = threadIdx.x & 63;
    const int w = __builtin_amdgcn_readfirstlane(threadIdx.x >> 6);
    const int rc = ((blockIdx.x & 15) << 2) | w;     // 64 row-chunks per bh
    const int b = bh >> 4, h = bh & 15;
    const int row = (rc << 6) | lane;

    const float* qp = Q + ((size_t)b * L_ + row) * E_ + h * D_;
    const float* kvb = kvf + (size_t)bh * ST2_;      // uniform base

    float ph[64];
    #pragma unroll
    for (int i = 0; i < 16; ++i) {
        const float4 q = ((const float4*)qp)[i];     // per-lane (own row)
        ph[4*i+0] = sigk(q.x);
        ph[4*i+1] = sigk(q.y);
        ph[4*i+2] = sigk(q.z);
        ph[4*i+3] = sigk(q.w);
    }

    float den = 0.f;
    #pragma unroll
    for (int i = 0; i < 16; ++i) {
        const float4 s = ((const float4*)(kvb + 4096))[i];   // uniform ksum
        den = fmaf(ph[4*i+0], s.x, den);
        den = fmaf(ph[4*i+1], s.y, den);
        den = fmaf(ph[4*i+2], s.z, den);
        den = fmaf(ph[4*i+3], s.w, den);
    }
    const float inv = __builtin_amdgcn_rcpf(den);

    float* op = out + ((size_t)b * L_ + row) * E_ + h * D_;
    #pragma unroll 1
    for (int e0 = 0; e0 < 64; e0 += 4) {
        float4 a;
        a.x = dot64(kvb + ((e0 + 0) << 6), ph) * inv;
        a.y = dot64(kvb + ((e0 + 1) << 6), ph) * inv;
        a.z = dot64(kvb + ((e0 + 2) << 6), ph) * inv;
        a.w = dot64(kvb + ((e0 + 3) << 6), ph) * inv;
        ((float4*)op)[e0 >> 2] = a;
    }
}

extern "C" void kernel_launch(void* const* d_in, const int* in_sizes, int n_in,
                              void* d_out, int out_size, void* d_ws, size_t ws_size,
                              hipStream_t stream) {
    const float* Q = (const float*)d_in[0];
    const float* K = (const float*)d_in[1];
    const float* V = (const float*)d_in[2];
    float* out = (float*)d_out;

    float* partial = (float*)d_ws;                        // NCH_*BH_*ST2_ (~17 MB)
    float* kvf     = partial + (size_t)NCH_ * BH_ * ST2_; // BH_*ST2_ (~1 MB)

    hipLaunchKernelGGL(kv_partial_kernel, dim3(BH_ * NCH_), dim3(256), 0, stream,
                       K, V, partial);
    hipLaunchKernelGGL(kv_reduce_kernel, dim3(BH_ * 4), dim3(256), 0, stream,
                       partial, kvf);
    hipLaunchKernelGGL(attn_out_kernel, dim3(BH_ * 16), dim3(256), 0, stream,
                       Q, kvf, out);
}

// Round 8
// 115.662 us; speedup vs baseline: 1.6799x; 1.6799x over previous
//
#include <hip/hip_runtime.h>
#include <cstdint>
#include <cstddef>

#define B_ 4
#define L_ 4096
#define E_ 1024
#define H_ 16
#define D_ 64
#define BH_ 64
#define ST2_ 4160        // 4096 kv + 64 ksum
#define NCH_ 16
#define RPC_ (L_/NCH_)   // 256 k-rows per chunk

typedef __attribute__((ext_vector_type(8))) short short8v;
typedef __attribute__((ext_vector_type(4))) float f32x4;

__device__ __forceinline__ float sigk(float x) {
    // sigmoid(0.6053*x - 4.102) = 1/(1+exp(4.102 - 0.6053*x))
    return __builtin_amdgcn_rcpf(1.0f + __expf(4.102f - 0.6053f * x));
}
// fp32 -> bf16 (RNE) and back, bit ops only
__device__ __forceinline__ unsigned short bfh(float f) {
    union { float f; unsigned u; } v; v.f = f;
    const unsigned r = v.u + 0x7fffu + ((v.u >> 16) & 1u);
    return (unsigned short)(r >> 16);
}
__device__ __forceinline__ float bf2f(unsigned short s) {
    union { unsigned u; float f; } v; v.u = ((unsigned)s) << 16;
    return v.f;
}

// MFMA 16x16x32_bf16 layouts (HW-verified, learn_hip m89/m156/m162):
//   A: lane l holds A[m=l&15][k=4*(l>>4)+(j&3)+16*(j>>2)], j=0..7
//   B: lane l holds B[k(same)][n=l&15]
//   C: lane l, reg r holds C[row=4*(l>>4)+r][col=l&15]

// ---------------- Kernel 1: partial kv[d][e] per (b,h,chunk) ----------------
// No LDS for data. Wave w owns d-slice [16w,16w+16). Fragments built directly
// from global; kv = phiK_bf16 x (V_hi + V_lo); ksum accumulates the SAME
// rounded phi values in fp32 (num/den weight consistency).
__global__ void __launch_bounds__(256) kv_partial_kernel(
    const float* __restrict__ K, const float* __restrict__ V,
    float* __restrict__ partial)
{
    const int ch = blockIdx.x & (NCH_ - 1);
    const int bh = blockIdx.x / NCH_;
    const int b = bh >> 4, h = bh & 15;
    const int tid = threadIdx.x;
    const int w = tid >> 6, l = tid & 63;
    const int g = l >> 4, m = l & 15;
    const int k4 = g << 2;
    const int d = (w << 4) + m;

    const float* Kp = K + (size_t)(b * L_ + ch * RPC_) * E_ + h * D_;
    const float* Vp = V + (size_t)(b * L_ + ch * RPC_) * E_ + h * D_;

    f32x4 acc[4];
    #pragma unroll
    for (int t = 0; t < 4; ++t) acc[t] = (f32x4){0.f, 0.f, 0.f, 0.f};
    float ksacc = 0.f;

    for (int ks = 0; ks < RPC_; ks += 32) {
        // A fragment: phi(K) for this wave's 16 d's, k in lane coverage
        float a[8];
        #pragma unroll
        for (int j = 0; j < 8; ++j) {
            const int ko = ks + k4 + (j & 3) + ((j >> 2) << 4);
            a[j] = Kp[(size_t)ko * E_ + d];
        }
        short8v Ah;
        #pragma unroll
        for (int j = 0; j < 8; ++j) {
            const unsigned short hb = bfh(sigk(a[j]));
            Ah[j] = (short)hb;
            ksacc += bf2f(hb);            // exact same weights as the MFMA
        }
        #pragma unroll
        for (int t = 0; t < 4; ++t) {
            float bv[8];
            #pragma unroll
            for (int j = 0; j < 8; ++j) {
                const int ko = ks + k4 + (j & 3) + ((j >> 2) << 4);
                bv[j] = Vp[(size_t)ko * E_ + (t << 4) + m];
            }
            short8v Bh, Bl;
            #pragma unroll
            for (int j = 0; j < 8; ++j) {
                const unsigned short hb = bfh(bv[j]);
                Bh[j] = (short)hb;
                Bl[j] = (short)bfh(bv[j] - bf2f(hb));
            }
            acc[t] = __builtin_amdgcn_mfma_f32_16x16x32_bf16(Ah, Bh, acc[t], 0, 0, 0);
            acc[t] = __builtin_amdgcn_mfma_f32_16x16x32_bf16(Ah, Bl, acc[t], 0, 0, 0);
        }
        __syncthreads();   // lockstep waves -> L1 reuse of shared V lines
    }

    // ksum[d]: combine the 4 lane-groups (same m, different k coverage)
    ksacc += __shfl_xor(ksacc, 16);
    ksacc += __shfl_xor(ksacc, 32);

    const size_t pbase = ((size_t)ch * BH_ + bh) * ST2_;
    #pragma unroll
    for (int t = 0; t < 4; ++t)
        #pragma unroll
        for (int r = 0; r < 4; ++r)
            partial[pbase + (size_t)((w << 4) + (g << 2) + r) * 64 + (t << 4) + m]
                = acc[t][r];
    if (g == 0) partial[pbase + 4096 + (w << 4) + m] = ksacc;
}

// ---- Kernel 2: reduce partials -> packed bf16 hi/lo kv + fp32 ksum ----
__global__ void __launch_bounds__(256) kv_reduce_kernel(
    const float* __restrict__ partial, unsigned* __restrict__ kv2,
    float* __restrict__ ksumf)
{
    const int bh = blockIdx.x;
    const int tid = threadIdx.x;
    #pragma unroll 4
    for (int i = 0; i < 16; ++i) {
        const int idx = tid + (i << 8);
        float s = 0.f;
        #pragma unroll
        for (int c = 0; c < NCH_; ++c)
            s += partial[((size_t)c * BH_ + bh) * ST2_ + idx];
        const unsigned short hb = bfh(s);
        const unsigned short lb = bfh(s - bf2f(hb));
        kv2[(size_t)bh * 4096 + idx] = ((unsigned)hb << 16) | (unsigned)lb;
    }
    if (tid < 64) {
        float s = 0.f;
        #pragma unroll
        for (int c = 0; c < NCH_; ++c)
            s += partial[((size_t)c * BH_ + bh) * ST2_ + 4096 + tid];
        ksumf[bh * 64 + tid] = s;
    }
}

// ---------------- Kernel 3: out = (phiQ @ kv) / (phiQ @ ksum) ----------------
// kv fragments staged once per block in LDS (fragment-major: lane-contiguous
// 16B reads). A = phiQ hi+lo, B = kv hi+lo (3 MFMA products). den in fp32 VALU.
__global__ void __launch_bounds__(256) attn_out_kernel(
    const float* __restrict__ Q, const unsigned* __restrict__ kv2,
    const float* __restrict__ ksumf, float* __restrict__ out)
{
    __shared__ short8v fragBv[16 * 64];   // [kstep(2)][t(4)][half(2)][lane(64)]
    unsigned short* fragB = (unsigned short*)fragBv;

    const int bh = blockIdx.x >> 5, qb = blockIdx.x & 31;
    const int b = bh >> 4, h = bh & 15;
    const int tid = threadIdx.x;
    const int w = tid >> 6, l = tid & 63;
    const int g = l >> 4, m = l & 15;
    const int k4 = g << 2;

    // stage kv fragments
    #pragma unroll 4
    for (int i = 0; i < 16; ++i) {
        const int idx = tid + (i << 8);
        const unsigned u = kv2[(size_t)bh * 4096 + idx];
        const int dd = idx >> 6, e = idx & 63;
        const int kk = dd & 31, kstep = dd >> 5;
        const int gg = (kk & 15) >> 2;
        const int jj = (kk & 3) + ((kk >> 4) << 2);
        const int lane = (e & 15) + (gg << 4);
        const int t = e >> 4;
        const int slot = (((kstep << 2) + t) << 1);
        fragB[(slot * 64 + lane) * 8 + jj]       = (unsigned short)(u >> 16);
        fragB[((slot + 1) * 64 + lane) * 8 + jj] = (unsigned short)(u & 0xffffu);
    }
    // this lane's ksum values (fixed per lane-group)
    float ksl[16];
    #pragma unroll
    for (int ks = 0; ks < 2; ++ks)
        #pragma unroll
        for (int j = 0; j < 8; ++j)
            ksl[ks * 8 + j] =
                ksumf[bh * 64 + (ks << 5) + k4 + (j & 3) + ((j >> 2) << 4)];
    __syncthreads();

    for (int qt = 0; qt < 2; ++qt) {
        const int rowb = (qb << 7) + (qt << 6) + (w << 4);
        const float* qp = Q + (size_t)(b * L_ + rowb + m) * E_ + h * D_;

        short8v Ah[2], Al[2];
        float den = 0.f;
        #pragma unroll
        for (int ks = 0; ks < 2; ++ks)
            #pragma unroll
            for (int j = 0; j < 8; ++j) {
                const float qv = qp[(ks << 5) + k4 + (j & 3) + ((j >> 2) << 4)];
                const float ph = sigk(qv);
                const unsigned short hb = bfh(ph);
                Ah[ks][j] = (short)hb;
                Al[ks][j] = (short)bfh(ph - bf2f(hb));
                den = fmaf(ph, ksl[ks * 8 + j], den);
            }

        f32x4 acc[4];
        #pragma unroll
        for (int t = 0; t < 4; ++t) acc[t] = (f32x4){0.f, 0.f, 0.f, 0.f};
        #pragma unroll
        for (int ks = 0; ks < 2; ++ks)
            #pragma unroll
            for (int t = 0; t < 4; ++t) {
                const int slot = (((ks << 2) + t) << 1);
                const short8v Bh = fragBv[slot * 64 + l];
                const short8v Bl = fragBv[(slot + 1) * 64 + l];
                acc[t] = __builtin_amdgcn_mfma_f32_16x16x32_bf16(Ah[ks], Bh, acc[t], 0, 0, 0);
                acc[t] = __builtin_amdgcn_mfma_f32_16x16x32_bf16(Ah[ks], Bl, acc[t], 0, 0, 0);
                acc[t] = __builtin_amdgcn_mfma_f32_16x16x32_bf16(Al[ks], Bh, acc[t], 0, 0, 0);
            }

        // den[m] = full dot for q-row m after combining the 4 lane-groups
        den += __shfl_xor(den, 16);
        den += __shfl_xor(den, 32);
        float inv[4];
        #pragma unroll
        for (int r = 0; r < 4; ++r)
            inv[r] = __builtin_amdgcn_rcpf(__shfl(den, k4 + r));

        float* op = out + (size_t)(b * L_ + rowb) * E_ + h * D_;
        #pragma unroll
        for (int t = 0; t < 4; ++t)
            #pragma unroll
            for (int r = 0; r < 4; ++r)
                op[(size_t)(k4 + r) * E_ + (t << 4) + m] = acc[t][r] * inv[r];
    }
}

extern "C" void kernel_launch(void* const* d_in, const int* in_sizes, int n_in,
                              void* d_out, int out_size, void* d_ws, size_t ws_size,
                              hipStream_t stream) {
    const float* Q = (const float*)d_in[0];
    const float* K = (const float*)d_in[1];
    const float* V = (const float*)d_in[2];
    float* out = (float*)d_out;

    float* partial  = (float*)d_ws;                              // NCH_*BH_*ST2_ f32 (~17 MB)
    unsigned* kv2   = (unsigned*)(partial + (size_t)NCH_ * BH_ * ST2_); // 64*4096 u32 (1 MB)
    float* ksumf    = (float*)(kv2 + (size_t)BH_ * 4096);        // 64*64 f32

    hipLaunchKernelGGL(kv_partial_kernel, dim3(BH_ * NCH_), dim3(256), 0, stream,
                       K, V, partial);
    hipLaunchKernelGGL(kv_reduce_kernel, dim3(BH_), dim3(256), 0, stream,
                       partial, kv2, ksumf);
    hipLaunchKernelGGL(attn_out_kernel, dim3(BH_ * 32), dim3(256), 0, stream,
                       Q, kv2, ksumf, out);
}

// Round 9
// 69.817 us; speedup vs baseline: 2.7830x; 1.6567x over previous
//
#include <hip/hip_runtime.h>
#include <cstdint>
#include <cstddef>

#define B_ 4
#define L_ 4096
#define E_ 1024
#define H_ 16
#define D_ 64
#define BH_ 64
#define ST2_ 4160        // 4096 kv + 64 ksum
#define NCH_ 16
#define RPC_ (L_/NCH_)   // 256 k-rows per chunk
#define NT_ (RPC_/32)    // 8 tiles of 32 k-rows

typedef __attribute__((ext_vector_type(8))) short short8v;
typedef __attribute__((ext_vector_type(4))) float f32x4;

__device__ __forceinline__ float sigk(float x) {
    // sigmoid(0.6053*x - 4.102) = 1/(1+exp(4.102 - 0.6053*x))
    return __builtin_amdgcn_rcpf(1.0f + __expf(4.102f - 0.6053f * x));
}
// fp32 -> bf16 (RNE) and back, bit ops only
__device__ __forceinline__ unsigned short bfh(float f) {
    union { float f; unsigned u; } v; v.f = f;
    const unsigned r = v.u + 0x7fffu + ((v.u >> 16) & 1u);
    return (unsigned short)(r >> 16);
}
__device__ __forceinline__ float bf2f(unsigned short s) {
    union { unsigned u; float f; } v; v.u = ((unsigned)s) << 16;
    return v.f;
}

// MFMA 16x16x32_bf16 layouts (HW-verified, learn_hip m89/m156/m162):
//   A: lane l holds A[m=l&15][k=4*(l>>4)+(j&3)+16*(j>>2)], j=0..7
//   B: lane l holds B[k(same)][n=l&15]
//   C: lane l, reg r holds C[row=4*(l>>4)+r][col=l&15]

// ---------------- Kernel 1: partial kv[d][e] per (b,h,chunk) ----------------
// V hi/lo converted ONCE per tile by 256 threads (1 fragment slot each) into
// double-buffered LDS; block-wide gathers are 4x256B coalesced. Each wave owns
// d-slice [16w,16w+16): A = phi(K) built from private reg-prefetched gathers.
// ksum accumulates the SAME rounded phi values (num/den weight consistency).
__global__ void __launch_bounds__(256) kv_partial_kernel(
    const float* __restrict__ K, const float* __restrict__ V,
    float* __restrict__ partial)
{
    __shared__ short8v Bfrag[2 * 8 * 64];   // [buf][t*2+hl][lane], 16 KB

    const int ch = blockIdx.x & (NCH_ - 1);
    const int bh = blockIdx.x / NCH_;
    const int b = bh >> 4, h = bh & 15;
    const int tid = threadIdx.x;
    const int w = tid >> 6, l = tid & 63;
    const int g = l >> 4, m = l & 15;
    const int k4 = g << 2;
    const int col = (w << 4) + m;   // V-stage column (t=w) == A d-column

    const float* Kp = K + (size_t)(b * L_ + ch * RPC_) * E_ + h * D_ + col;
    const float* Vp = V + (size_t)(b * L_ + ch * RPC_) * E_ + h * D_ + col;

    f32x4 acc[4];
    #pragma unroll
    for (int t = 0; t < 4; ++t) acc[t] = (f32x4){0.f, 0.f, 0.f, 0.f};
    float ksacc = 0.f;

    float vr[8], kr[8];
    #pragma unroll
    for (int j = 0; j < 8; ++j) {
        const int ko = k4 + (j & 3) + ((j >> 2) << 4);
        vr[j] = Vp[(size_t)ko * E_];
        kr[j] = Kp[(size_t)ko * E_];
    }
    {   // stage tile 0 (this thread's slot: t=w, lane l)
        short8v Bh, Bl;
        #pragma unroll
        for (int j = 0; j < 8; ++j) {
            const unsigned short hb = bfh(vr[j]);
            Bh[j] = (short)hb;
            Bl[j] = (short)bfh(vr[j] - bf2f(hb));
        }
        Bfrag[(w << 1) * 64 + l]       = Bh;
        Bfrag[((w << 1) + 1) * 64 + l] = Bl;
    }
    __syncthreads();

    #pragma unroll 2
    for (int t = 0; t < NT_; ++t) {
        const int buf = (t & 1) << 9;
        float vr2[8], kr2[8];
        if (t + 1 < NT_) {   // issue next tile's loads; land during MFMA
            #pragma unroll
            for (int j = 0; j < 8; ++j) {
                const int ko = ((t + 1) << 5) + k4 + (j & 3) + ((j >> 2) << 4);
                vr2[j] = Vp[(size_t)ko * E_];
                kr2[j] = Kp[(size_t)ko * E_];
            }
        }
        short8v Ah;
        #pragma unroll
        for (int j = 0; j < 8; ++j) {
            const unsigned short hb = bfh(sigk(kr[j]));
            Ah[j] = (short)hb;
            ksacc += bf2f(hb);          // exact same weights as the MFMA
        }
        #pragma unroll
        for (int tt = 0; tt < 4; ++tt) {
            const short8v Bh = Bfrag[buf + (tt << 1) * 64 + l];
            const short8v Bl = Bfrag[buf + ((tt << 1) + 1) * 64 + l];
            acc[tt] = __builtin_amdgcn_mfma_f32_16x16x32_bf16(Ah, Bh, acc[tt], 0, 0, 0);
            acc[tt] = __builtin_amdgcn_mfma_f32_16x16x32_bf16(Ah, Bl, acc[tt], 0, 0, 0);
        }
        if (t + 1 < NT_) {   // convert + stage next tile into other buffer
            const int nbuf = ((t + 1) & 1) << 9;
            short8v Bh, Bl;
            #pragma unroll
            for (int j = 0; j < 8; ++j) {
                const unsigned short hb = bfh(vr2[j]);
                Bh[j] = (short)hb;
                Bl[j] = (short)bfh(vr2[j] - bf2f(hb));
            }
            Bfrag[nbuf + (w << 1) * 64 + l]       = Bh;
            Bfrag[nbuf + ((w << 1) + 1) * 64 + l] = Bl;
            #pragma unroll
            for (int j = 0; j < 8; ++j) kr[j] = kr2[j];
        }
        __syncthreads();
    }

    // ksum[d]: combine the 4 lane-groups (same m, different k coverage)
    ksacc += __shfl_xor(ksacc, 16);
    ksacc += __shfl_xor(ksacc, 32);

    const size_t pbase = ((size_t)ch * BH_ + bh) * ST2_;
    #pragma unroll
    for (int tt = 0; tt < 4; ++tt)
        #pragma unroll
        for (int r = 0; r < 4; ++r)
            partial[pbase + (size_t)((w << 4) + k4 + r) * 64 + (tt << 4) + m]
                = acc[tt][r];
    if (g == 0) partial[pbase + 4096 + (w << 4) + m] = ksacc;
}

// ---- Kernel 2: reduce partials -> packed bf16 hi/lo kv + fp32 ksum ----
__global__ void __launch_bounds__(256) kv_reduce_kernel(
    const float* __restrict__ partial, unsigned* __restrict__ kv2,
    float* __restrict__ ksumf)
{
    const int bh = blockIdx.x >> 2, part = blockIdx.x & 3;
    const int tid = threadIdx.x;
    #pragma unroll
    for (int i = 0; i < 4; ++i) {
        const int idx = (part << 10) + (i << 8) + tid;
        float s = 0.f;
        #pragma unroll
        for (int c = 0; c < NCH_; ++c)
            s += partial[((size_t)c * BH_ + bh) * ST2_ + idx];
        const unsigned short hb = bfh(s);
        const unsigned short lb = bfh(s - bf2f(hb));
        kv2[(size_t)bh * 4096 + idx] = ((unsigned)hb << 16) | (unsigned)lb;
    }
    if (part == 0 && tid < 64) {
        float s = 0.f;
        #pragma unroll
        for (int c = 0; c < NCH_; ++c)
            s += partial[((size_t)c * BH_ + bh) * ST2_ + 4096 + tid];
        ksumf[bh * 64 + tid] = s;
    }
}

// ---------------- Kernel 3: out = (phiQ @ kv) / (phiQ @ ksum) ----------------
// kv fragments staged once per block in LDS; Q tile staged per 64-row group
// via coalesced float4 loads (fixes the 16-segment per-lane row gathers),
// fragment-gathered from padded LDS (stride 65 -> <=4-way conflicts).
__global__ void __launch_bounds__(256) attn_out_kernel(
    const float* __restrict__ Q, const unsigned* __restrict__ kv2,
    const float* __restrict__ ksumf, float* __restrict__ out)
{
    __shared__ short8v fragBv[16 * 64];   // [kstep(2)][t(4)][half(2)][lane], 16 KB
    __shared__ float Qt[64 * 65];         // padded Q tile, 16.6 KB
    unsigned short* fragB = (unsigned short*)fragBv;

    const int bh = blockIdx.x >> 5, qb = blockIdx.x & 31;
    const int b = bh >> 4, h = bh & 15;
    const int tid = threadIdx.x;
    const int w = tid >> 6, l = tid & 63;
    const int g = l >> 4, m = l & 15;
    const int k4 = g << 2;

    // stage kv fragments
    #pragma unroll 4
    for (int i = 0; i < 16; ++i) {
        const int idx = tid + (i << 8);
        const unsigned u = kv2[(size_t)bh * 4096 + idx];
        const int dd = idx >> 6, e = idx & 63;
        const int kk = dd & 31, kstep = dd >> 5;
        const int gg = (kk & 15) >> 2;
        const int jj = (kk & 3) + ((kk >> 4) << 2);
        const int lane = (e & 15) + (gg << 4);
        const int tt2 = e >> 4;
        const int slot = (((kstep << 2) + tt2) << 1);
        fragB[(slot * 64 + lane) * 8 + jj]       = (unsigned short)(u >> 16);
        fragB[((slot + 1) * 64 + lane) * 8 + jj] = (unsigned short)(u & 0xffffu);
    }
    float ksl[16];
    #pragma unroll
    for (int ks = 0; ks < 2; ++ks)
        #pragma unroll
        for (int j = 0; j < 8; ++j)
            ksl[ks * 8 + j] =
                ksumf[bh * 64 + (ks << 5) + k4 + (j & 3) + ((j >> 2) << 4)];
    __syncthreads();

    for (int qt = 0; qt < 2; ++qt) {
        const int rowb0 = (qb << 7) + (qt << 6);
        // stage 64 Q rows, coalesced (16 segments x 256B per instruction)
        #pragma unroll
        for (int i = 0; i < 4; ++i) {
            const int idx = tid + (i << 8);
            const int r = idx >> 4, c4i = (idx & 15) << 2;
            const float4 qv = *(const float4*)(
                Q + (size_t)(b * L_ + rowb0 + r) * E_ + h * D_ + c4i);
            float* qd = Qt + r * 65 + c4i;
            qd[0] = qv.x; qd[1] = qv.y; qd[2] = qv.z; qd[3] = qv.w;
        }
        __syncthreads();

        const int rl = (w << 4) + m;         // this lane's q-row (tile-local)
        short8v Ah[2], Al[2];
        float den = 0.f;
        #pragma unroll
        for (int ks = 0; ks < 2; ++ks)
            #pragma unroll
            for (int j = 0; j < 8; ++j) {
                const float qv =
                    Qt[rl * 65 + (ks << 5) + k4 + (j & 3) + ((j >> 2) << 4)];
                const float ph = sigk(qv);
                const unsigned short hb = bfh(ph);
                Ah[ks][j] = (short)hb;
                Al[ks][j] = (short)bfh(ph - bf2f(hb));
                den = fmaf(ph, ksl[ks * 8 + j], den);
            }

        f32x4 acc[4];
        #pragma unroll
        for (int tt = 0; tt < 4; ++tt) acc[tt] = (f32x4){0.f, 0.f, 0.f, 0.f};
        #pragma unroll
        for (int ks = 0; ks < 2; ++ks)
            #pragma unroll
            for (int tt = 0; tt < 4; ++tt) {
                const int slot = (((ks << 2) + tt) << 1);
                const short8v Bh = fragBv[slot * 64 + l];
                const short8v Bl = fragBv[(slot + 1) * 64 + l];
                acc[tt] = __builtin_amdgcn_mfma_f32_16x16x32_bf16(Ah[ks], Bh, acc[tt], 0, 0, 0);
                acc[tt] = __builtin_amdgcn_mfma_f32_16x16x32_bf16(Ah[ks], Bl, acc[tt], 0, 0, 0);
                acc[tt] = __builtin_amdgcn_mfma_f32_16x16x32_bf16(Al[ks], Bh, acc[tt], 0, 0, 0);
            }

        den += __shfl_xor(den, 16);
        den += __shfl_xor(den, 32);
        float inv[4];
        #pragma unroll
        for (int r = 0; r < 4; ++r)
            inv[r] = __builtin_amdgcn_rcpf(__shfl(den, k4 + r));

        float* op = out + (size_t)(b * L_ + rowb0 + (w << 4)) * E_ + h * D_;
        #pragma unroll
        for (int tt = 0; tt < 4; ++tt)
            #pragma unroll
            for (int r = 0; r < 4; ++r)
                op[(size_t)(k4 + r) * E_ + (tt << 4) + m] = acc[tt][r] * inv[r];
        __syncthreads();   // Qt reused next qt
    }
}

extern "C" void kernel_launch(void* const* d_in, const int* in_sizes, int n_in,
                              void* d_out, int out_size, void* d_ws, size_t ws_size,
                              hipStream_t stream) {
    const float* Q = (const float*)d_in[0];
    const float* K = (const float*)d_in[1];
    const float* V = (const float*)d_in[2];
    float* out = (float*)d_out;

    float* partial  = (float*)d_ws;                              // NCH_*BH_*ST2_ f32 (~17 MB)
    unsigned* kv2   = (unsigned*)(partial + (size_t)NCH_ * BH_ * ST2_); // 64*4096 u32 (1 MB)
    float* ksumf    = (float*)(kv2 + (size_t)BH_ * 4096);        // 64*64 f32

    hipLaunchKernelGGL(kv_partial_kernel, dim3(BH_ * NCH_), dim3(256), 0, stream,
                       K, V, partial);
    hipLaunchKernelGGL(kv_reduce_kernel, dim3(BH_ * 4), dim3(256), 0, stream,
                       partial, kv2, ksumf);
    hipLaunchKernelGGL(attn_out_kernel, dim3(BH_ * 32), dim3(256), 0, stream,
                       Q, kv2, ksumf, out);
}